// Round 9
// baseline (209.567 us; speedup 1.0000x reference)
//
#include <hip/hip_runtime.h>

typedef short bf16x8 __attribute__((ext_vector_type(8)));
typedef float floatx4 __attribute__((ext_vector_type(4)));
typedef unsigned short ushort4v __attribute__((ext_vector_type(4)));
typedef unsigned int uintx4 __attribute__((ext_vector_type(4)));
typedef unsigned int uintx2 __attribute__((ext_vector_type(2)));

#define HW 3136
#define WS 100   // attn LDS stride (floats) per pixel

// prep layout (floats)
#define P_CP   0
#define P_W1   4      // 288
#define P_W2   292    // 128
#define P_BN   424    // a1[HW], c1[HW], a2[HW], c2[HW]
#define PREP_FLOATS (424 + 4 * HW)

// ---- bf16 bit helpers (RNE) ----
__device__ __forceinline__ unsigned short f2bf(float f) {
    unsigned int u = __float_as_uint(f);
    unsigned int r = (u + 0x7FFFu + ((u >> 16) & 1u)) >> 16;
    return (unsigned short)r;
}
__device__ __forceinline__ float bf2f(unsigned short u) {
    return __uint_as_float(((unsigned int)u) << 16);
}
__device__ __forceinline__ void unp8(uint4 u, float* o) {
    o[0] = bf2f((unsigned short)(u.x & 0xFFFFu)); o[1] = bf2f((unsigned short)(u.x >> 16));
    o[2] = bf2f((unsigned short)(u.y & 0xFFFFu)); o[3] = bf2f((unsigned short)(u.y >> 16));
    o[4] = bf2f((unsigned short)(u.z & 0xFFFFu)); o[5] = bf2f((unsigned short)(u.z >> 16));
    o[6] = bf2f((unsigned short)(u.w & 0xFFFFu)); o[7] = bf2f((unsigned short)(u.w >> 16));
}
__device__ __forceinline__ float ldp(const void* p, int i, int isb) {
    return isb ? bf2f(((const unsigned short*)p)[i]) : ((const float*)p)[i];
}

// ---------------------------------------------------------------------------
// proj v2b: LDS-shared B-fragments (round-8 win, kept) + A-fragment
// STREAMING. Occupancy model (m69): waves/SIMD = 8 at VGPR<=64, 4 at
// 65-128. (384,6) demands the 8-wave bin -> compiler forced to <=64 VGPR.
// v2's a[8] preload alone was 32 VGPR (total ~74 -> silent starve/spill).
// v2b rotates a 2-register A prefetch through the compute loop: live set
// ~50 <= 64, honestly spill-free, keeping 8 waves/SIMD -> 5 blocks/CU ->
// capacity 1280 >= 784, one scheduling round.
// Falsifier: proj WRITE_SIZE > 12 MB (9.7 expected) = still spilling.
// ---------------------------------------------------------------------------
template <int ISB>
__device__ __forceinline__ void stage_one(const void* x, size_t xpx, int s,
                                          int quad, int lane, uintx4* frag)
{
    const int ch0 = s * 32 + quad * 8;
    unsigned b[16];
    if (ISB) {
        const unsigned short* p = (const unsigned short*)x + xpx + (size_t)ch0 * HW;
        #pragma unroll
        for (int j = 0; j < 8; ++j)
            *(uintx2*)&b[2 * j] = *(const uintx2*)(p + (size_t)j * HW);
    } else {
        const float* p = (const float*)x + xpx + (size_t)ch0 * HW;
        #pragma unroll
        for (int j = 0; j < 8; ++j) {
            floatx4 f = *(const floatx4*)(p + (size_t)j * HW);
            b[2 * j]     = (unsigned)f2bf(f[0]) | ((unsigned)f2bf(f[1]) << 16);
            b[2 * j + 1] = (unsigned)f2bf(f[2]) | ((unsigned)f2bf(f[3]) << 16);
        }
    }
    #pragma unroll
    for (int t = 0; t < 4; ++t) {
        const int wi = t >> 1;
        uintx4 uv;
        #pragma unroll
        for (int d = 0; d < 4; ++d) {
            const unsigned lo = b[2 * (2 * d) + wi];
            const unsigned hi = b[2 * (2 * d + 1) + wi];
            uv[d] = (t & 1) ? ((lo >> 16) | (hi & 0xFFFF0000u))
                            : ((lo & 0xFFFFu) | (hi << 16));
        }
        frag[(s * 4 + t) * 64 + lane] = uv;
    }
}

template <int ISB>
__device__ __forceinline__ bf16x8 load_a(const void* wp, int arow, int quad, int s)
{
    if (ISB) {
        const unsigned short* fp = (const unsigned short*)wp + arow * 256 + quad * 8;
        return *(const bf16x8*)(fp + s * 32);
    } else {
        const float* fp = (const float*)wp + arow * 256 + quad * 8;
        floatx4 f0 = *(const floatx4*)(fp + s * 32);
        floatx4 f1 = *(const floatx4*)(fp + s * 32 + 4);
        bf16x8 av;
        #pragma unroll
        for (int j = 0; j < 4; ++j) {
            av[j]     = (short)f2bf(f0[j]);
            av[4 + j] = (short)f2bf(f1[j]);
        }
        return av;
    }
}

template <int ISB>
__global__ __launch_bounds__(384, 6) void proj_kernel(
    const void* __restrict__ x,
    const void* __restrict__ w1, const void* __restrict__ w2,
    const void* __restrict__ w3,
    const void* __restrict__ cpw, const void* __restrict__ cw1,
    const void* __restrict__ cw2,
    const void* __restrict__ b1g, const void* __restrict__ b1b,
    const void* __restrict__ b1m, const void* __restrict__ b1v,
    const void* __restrict__ b2g, const void* __restrict__ b2b,
    const void* __restrict__ b2m, const void* __restrict__ b2v,
    unsigned short* __restrict__ y12,
    unsigned short* __restrict__ y3a,
    float* __restrict__ prep)
{
    __shared__ uintx4 frag[8 * 4 * 64];    // [s][t][lane], 32 KB
    const int tid = threadIdx.x;

    // prep: 16 blocks x 196 px each; block 0 also copies CP|W1|W2.
    if (blockIdx.x < 16) {
        if (blockIdx.x == 0) {
            for (int i = tid; i < 420; i += 384) {
                float v;
                if      (i < 4)   v = ldp(cpw, i,        ISB);
                else if (i < 292) v = ldp(cw1, i - 4,    ISB);
                else              v = ldp(cw2, i - 292,  ISB);
                prep[i] = v;
            }
        }
        const int i0 = blockIdx.x * 196;
        if (tid < 196) {
            const int i = i0 + tid;
            float a1 = ldp(b1g, i, ISB) * rsqrtf(ldp(b1v, i, ISB) + 1e-3f);
            float c1 = ldp(b1b, i, ISB) - ldp(b1m, i, ISB) * a1;
            float a2 = ldp(b2g, i, ISB) * rsqrtf(ldp(b2v, i, ISB) + 1e-3f);
            float c2 = ldp(b2b, i, ISB) - ldp(b2m, i, ISB) * a2;
            prep[P_BN + i]          = a1;
            prep[P_BN + HW + i]     = c1;
            prep[P_BN + 2 * HW + i] = a2;
            prep[P_BN + 3 * HW + i] = c2;
        }
    }

    // block = one (n, px0); the 6 waves are the 6 row-tiles.
    const int n    = blockIdx.x / 49;
    const int pt   = blockIdx.x - n * 49;
    const int px0  = pt * 64;                      // 49 * 64 = 3136 exact
    const int rt   = tid >> 6;                     // 0..5, wave-uniform
    const int lane = tid & 63;
    const int col  = lane & 15, quad = lane >> 4;

    const size_t xpx = (size_t)n * 256 * HW + px0 + 4 * col;

    // ---- staging: wave rt builds stage rt (waves 0,1 also stages 6,7) ----
    stage_one<ISB>(x, xpx, rt, quad, lane, frag);
    if (rt < 2) stage_one<ISB>(x, xpx, 6 + rt, quad, lane, frag);

    const void* wp; int ro;
    if      (rt == 0) { wp = w1; ro = 0;  }
    else if (rt == 1) { wp = w2; ro = 0;  }
    else if (rt == 2) { wp = w3; ro = 0;  }
    else if (rt == 3) { wp = w3; ro = 16; }
    else if (rt == 4) { wp = w3; ro = 32; }
    else              { wp = w3; ro = 48; }
    const int arow = ro + col;

    // first A-fragment issued before the barrier (latency under the sync)
    bf16x8 a0 = load_a<ISB>(wp, arow, quad, 0);

    __syncthreads();

    // ---- compute: LDS + MFMA, A streamed with 1-deep prefetch ----
    floatx4 acc[4] = {};
    #pragma unroll
    for (int s = 0; s < 8; ++s) {
        bf16x8 a1v = (s < 7) ? load_a<ISB>(wp, arow, quad, s + 1) : a0;
        uintx4 f[4];
        #pragma unroll
        for (int t = 0; t < 4; ++t)
            f[t] = frag[(s * 4 + t) * 64 + lane];
        #pragma unroll
        for (int t = 0; t < 4; ++t)
            acc[t] = __builtin_amdgcn_mfma_f32_16x16x32_bf16(
                a0, __builtin_bit_cast(bf16x8, f[t]), acc[t], 0, 0, 0);
        a0 = a1v;
    }

    // D: ch = 16*rt + quad*4 + g, px = px0 + 4*col + tt
    const int chq = quad * 4;
    #pragma unroll
    for (int tt = 0; tt < 4; ++tt) {
        const int px = px0 + 4 * col + tt;
        ushort4v pk;
        #pragma unroll
        for (int g = 0; g < 4; ++g) pk[g] = f2bf(acc[tt][g]);
        if (rt < 2) {
            *(ushort4v*)(y12 + ((size_t)n * HW + px) * 32 + rt * 16 + chq) = pk;
        } else {
            const int k8 = 2 * (rt - 2) + (quad >> 1);
            *(ushort4v*)(y3a + (((size_t)n * 8 + k8) * HW + px) * 8 + (quad & 1) * 4) = pk;
        }
    }
}

// ---------------------------------------------------------------------------
// Fused attention v5: block = 512 threads (8 waves) = 64 pixels.
// Occupancy fix: 9-wave blocks capped at floor(32/9)=3 blocks/CU ->
// capacity 768 < grid 784 -> a 16-block TAIL ROUND, and 27/32 wave slots.
// 8-wave blocks: wave w owns j=w; wave 0 additionally does j=8 (the block
// imbalance is hidden by the 3 other co-resident blocks per CU — unlike
// round-6's all-waves-serial-j trap, the per-thread path stays one j).
// Phases 2/3 are exact 512-item fits (the old tid<512 gate is now the whole
// block). 4 blocks/CU (LDS allows 6) -> capacity 1024 >= 784: one round,
// 32/32 wave slots. (512,8) keeps VGPR in the 8-waves/SIMD bin (<=64).
// ---------------------------------------------------------------------------
template <int ISB>
__global__ __launch_bounds__(512, 8) void attn_kernel(
    const unsigned short* __restrict__ y12,
    const unsigned short* __restrict__ y3a,
    const float* __restrict__ prep,
    void* __restrict__ out)
{
    __shared__ float wsm[64 * WS];
    const int tid = threadIdx.x;
    const int blk = blockIdx.x;
    const int n   = blk / 49;
    const int l0  = (blk - n * 49) * 64;
    const int wv  = tid >> 6;          // 0..7, wave-uniform
    const int p   = tid & 63;
    const int l   = l0 + p;
    const int h   = l / 56, w = l - h * 56;

    // ---- phase 1: pre-softmax h2[8] per (pixel, j); wave 0 also j=8 ----
    {
        const float a1 = prep[P_BN + l];
        const float c1 = prep[P_BN + HW + l];
        const float a2 = prep[P_BN + 2 * HW + l];
        const float c2 = prep[P_BN + 3 * HW + l];

        const unsigned short* y1p = y12 + ((size_t)n * HW + l) * 32;

        const int nj = (wv == 0) ? 2 : 1;
        #pragma unroll 1
        for (int t = 0; t < nj; ++t) {
            const int j = t ? 8 : wv;
            const int dy = j / 3 - 1, dx = j - (j / 3) * 3 - 1;
            int hh = h + dy; hh = (hh < 0) ? -hh : ((hh > 55) ? 110 - hh : hh);
            int ww = w + dx; ww = (ww < 0) ? -ww : ((ww > 55) ? 110 - ww : ww);
            const int nbr = hh * 56 + ww;

            const unsigned short* y2p = y12 + ((size_t)n * HW + nbr) * 32 + 16;

            // fused unpack->rel per 8-wide half keeps the live set small.
            float rel[18];
            #pragma unroll
            for (int half = 0; half < 2; ++half) {
                uint4 u1 = *(const uint4*)(y1p + 8 * half);
                uint4 u2 = *(const uint4*)(y2p + 8 * half);
                float t1[8], t2[8];
                unp8(u1, t1);
                unp8(u2, t2);
                #pragma unroll
                for (int c = 0; c < 8; ++c)
                    rel[8 * half + c] = fmaxf(fmaf(t1[c] - t2[c], a1, c1), 0.f);
            }
            const float dlw = (float)(w - ww) * (2.0f / 55.0f);
            const float dlh = (float)(h - hh) * (2.0f / 55.0f);
            rel[16] = fmaxf(fmaf(prep[P_CP + 0] * dlw + prep[P_CP + 1] * dlh, a1, c1), 0.f);
            rel[17] = fmaxf(fmaf(prep[P_CP + 2] * dlw + prep[P_CP + 3] * dlh, a1, c1), 0.f);

            float h1[16];
            #pragma unroll
            for (int o = 0; o < 16; ++o) {
                float s = 0.f;
                #pragma unroll
                for (int c = 0; c < 18; ++c)
                    s = fmaf(prep[P_W1 + o * 18 + c], rel[c], s);
                h1[o] = fmaxf(fmaf(s, a2, c2), 0.f);
            }
            float h2[8];
            #pragma unroll
            for (int o2 = 0; o2 < 8; ++o2) {
                float s = 0.f;
                #pragma unroll
                for (int o = 0; o < 16; ++o)
                    s = fmaf(prep[P_W2 + o2 * 16 + o], h1[o], s);
                h2[o2] = s;
            }
            float* wpt = &wsm[p * WS + j * 8];
            *(floatx4*)wpt       = *(floatx4*)&h2[0];
            *(floatx4*)(wpt + 4) = *(floatx4*)&h2[4];
        }
    }
    __syncthreads();

    // ---- phase 2: softmax over j; exactly 512 items = 512 threads ----
    {
        const int c = tid & 7, pp = tid >> 3;
        float v[9];
        #pragma unroll
        for (int j = 0; j < 9; ++j) v[j] = wsm[pp * WS + j * 8 + c];
        float m = v[0];
        #pragma unroll
        for (int j = 1; j < 9; ++j) m = fmaxf(m, v[j]);
        float s = 0.f;
        #pragma unroll
        for (int j = 0; j < 9; ++j) { v[j] = __expf(v[j] - m); s += v[j]; }
        const float inv = 1.f / s;
        #pragma unroll
        for (int j = 0; j < 9; ++j) wsm[pp * WS + j * 8 + c] = v[j] * inv;
    }
    __syncthreads();

    // ---- phase 3: aggregation; wave wv = channel-group k8 = wv ----
    {
        const int k8 = wv;
        int nbr[9];
        #pragma unroll
        for (int dy = 0; dy < 3; ++dy)
            #pragma unroll
            for (int dx = 0; dx < 3; ++dx) {
                int hh = h + dy - 1; hh = (hh < 0) ? -hh : ((hh > 55) ? 110 - hh : hh);
                int ww = w + dx - 1; ww = (ww < 0) ? -ww : ((ww > 55) ? 110 - ww : ww);
                nbr[dy * 3 + dx] = hh * 56 + ww;
            }
        const unsigned short* y3b = y3a + ((size_t)n * 8 + k8) * HW * 8;
        float acc8[8];
        #pragma unroll
        for (int k = 0; k < 8; ++k) acc8[k] = 0.f;
        #pragma unroll
        for (int j = 0; j < 9; ++j) {
            uint4 u = *(const uint4*)(y3b + (size_t)nbr[j] * 8);
            float yv[8];
            unp8(u, yv);
            const float* wpt = &wsm[p * WS + j * 8];
            #pragma unroll
            for (int k = 0; k < 8; ++k)
                acc8[k] = fmaf(wpt[k], yv[k], acc8[k]);
        }
        const size_t obase = ((size_t)n * 64 + k8 * 8) * HW + l;
        #pragma unroll
        for (int k = 0; k < 8; ++k) {
            if (ISB) ((unsigned short*)out)[obase + (size_t)k * HW] = f2bf(acc8[k]);
            else     ((float*)out)[obase + (size_t)k * HW]          = acc8[k];
        }
    }
}

extern "C" void kernel_launch(void* const* d_in, const int* in_sizes, int n_in,
                              void* d_out, int out_size, void* d_ws, size_t ws_size,
                              hipStream_t stream)
{
    const size_t y12B = (size_t)16 * HW * 32 * 2;      // 3,211,264 B
    const size_t y3aB = (size_t)16 * 8 * HW * 8 * 2;   // 6,422,528 B

    unsigned short* y12 = (unsigned short*)d_ws;
    unsigned short* y3a = (unsigned short*)((char*)d_ws + y12B);
    float* prep = (float*)((char*)d_ws + y12B + y3aB);

    // dtype detect on HOST: bn1_var is [3136] -> 6272 B bf16, 12544 B fp32.
    const int isb = (in_sizes[10] == HW * 2);

    if (isb) {
        proj_kernel<1><<<dim3(784), dim3(384), 0, stream>>>(
            d_in[0], d_in[1], d_in[2], d_in[3],
            d_in[4], d_in[5], d_in[6],
            d_in[7], d_in[8], d_in[9], d_in[10],
            d_in[11], d_in[12], d_in[13], d_in[14],
            y12, y3a, prep);
        attn_kernel<1><<<dim3(784), dim3(512), 0, stream>>>(y12, y3a, prep, d_out);
    } else {
        proj_kernel<0><<<dim3(784), dim3(384), 0, stream>>>(
            d_in[0], d_in[1], d_in[2], d_in[3],
            d_in[4], d_in[5], d_in[6],
            d_in[7], d_in[8], d_in[9], d_in[10],
            d_in[11], d_in[12], d_in[13], d_in[14],
            y12, y3a, prep);
        attn_kernel<0><<<dim3(784), dim3(512), 0, stream>>>(y12, y3a, prep, d_out);
    }
}

// Round 10
// 140.172 us; speedup vs baseline: 1.4951x; 1.4951x over previous
//
#include <hip/hip_runtime.h>

typedef short bf16x8 __attribute__((ext_vector_type(8)));
typedef float floatx4 __attribute__((ext_vector_type(4)));
typedef unsigned short ushort4v __attribute__((ext_vector_type(4)));
typedef unsigned int uintx4 __attribute__((ext_vector_type(4)));
typedef unsigned int uintx2 __attribute__((ext_vector_type(2)));

#define HW 3136
#define WS 100   // attn LDS stride (floats) per pixel

// prep layout (floats)
#define P_CP   0
#define P_W1   4      // 288
#define P_W2   292    // 128
#define P_BN   424    // a1[HW], c1[HW], a2[HW], c2[HW]
#define PREP_FLOATS (424 + 4 * HW)

// ---- bf16 bit helpers (RNE) ----
__device__ __forceinline__ unsigned short f2bf(float f) {
    unsigned int u = __float_as_uint(f);
    unsigned int r = (u + 0x7FFFu + ((u >> 16) & 1u)) >> 16;
    return (unsigned short)r;
}
__device__ __forceinline__ float bf2f(unsigned short u) {
    return __uint_as_float(((unsigned int)u) << 16);
}
__device__ __forceinline__ void unp8(uint4 u, float* o) {
    o[0] = bf2f((unsigned short)(u.x & 0xFFFFu)); o[1] = bf2f((unsigned short)(u.x >> 16));
    o[2] = bf2f((unsigned short)(u.y & 0xFFFFu)); o[3] = bf2f((unsigned short)(u.y >> 16));
    o[4] = bf2f((unsigned short)(u.z & 0xFFFFu)); o[5] = bf2f((unsigned short)(u.z >> 16));
    o[6] = bf2f((unsigned short)(u.w & 0xFFFFu)); o[7] = bf2f((unsigned short)(u.w >> 16));
}
__device__ __forceinline__ float ldp(const void* p, int i, int isb) {
    return isb ? bf2f(((const unsigned short*)p)[i]) : ((const float*)p)[i];
}

// ---------------------------------------------------------------------------
// proj v2b (kept from round 9): LDS-shared B-fragments + A-fragment
// streaming (1-deep rotating prefetch; live set ~50 <= 64 so the (384,6)
// 8-waves/SIMD bin is honest, no spill). Wave rt stages stage s=rt (waves
// 0,1 also 6,7) into frag[s][t][lane] (32KB, lane-contiguous both ways).
// SESSION RULE (confirmed 3x: rounds 2/3 proj, round 9 attn): never demand
// min-waves that forces VGPR below the live set -- the allocator spills to
// scratch (+17-22MB WRITE, 2-4x slowdown). (384,6) is safe ONLY because the
// streamed live set genuinely fits 64 VGPR.
// ---------------------------------------------------------------------------
template <int ISB>
__device__ __forceinline__ void stage_one(const void* x, size_t xpx, int s,
                                          int quad, int lane, uintx4* frag)
{
    const int ch0 = s * 32 + quad * 8;
    unsigned b[16];
    if (ISB) {
        const unsigned short* p = (const unsigned short*)x + xpx + (size_t)ch0 * HW;
        #pragma unroll
        for (int j = 0; j < 8; ++j)
            *(uintx2*)&b[2 * j] = *(const uintx2*)(p + (size_t)j * HW);
    } else {
        const float* p = (const float*)x + xpx + (size_t)ch0 * HW;
        #pragma unroll
        for (int j = 0; j < 8; ++j) {
            floatx4 f = *(const floatx4*)(p + (size_t)j * HW);
            b[2 * j]     = (unsigned)f2bf(f[0]) | ((unsigned)f2bf(f[1]) << 16);
            b[2 * j + 1] = (unsigned)f2bf(f[2]) | ((unsigned)f2bf(f[3]) << 16);
        }
    }
    #pragma unroll
    for (int t = 0; t < 4; ++t) {
        const int wi = t >> 1;
        uintx4 uv;
        #pragma unroll
        for (int d = 0; d < 4; ++d) {
            const unsigned lo = b[2 * (2 * d) + wi];
            const unsigned hi = b[2 * (2 * d + 1) + wi];
            uv[d] = (t & 1) ? ((lo >> 16) | (hi & 0xFFFF0000u))
                            : ((lo & 0xFFFFu) | (hi << 16));
        }
        frag[(s * 4 + t) * 64 + lane] = uv;
    }
}

template <int ISB>
__device__ __forceinline__ bf16x8 load_a(const void* wp, int arow, int quad, int s)
{
    if (ISB) {
        const unsigned short* fp = (const unsigned short*)wp + arow * 256 + quad * 8;
        return *(const bf16x8*)(fp + s * 32);
    } else {
        const float* fp = (const float*)wp + arow * 256 + quad * 8;
        floatx4 f0 = *(const floatx4*)(fp + s * 32);
        floatx4 f1 = *(const floatx4*)(fp + s * 32 + 4);
        bf16x8 av;
        #pragma unroll
        for (int j = 0; j < 4; ++j) {
            av[j]     = (short)f2bf(f0[j]);
            av[4 + j] = (short)f2bf(f1[j]);
        }
        return av;
    }
}

template <int ISB>
__global__ __launch_bounds__(384, 6) void proj_kernel(
    const void* __restrict__ x,
    const void* __restrict__ w1, const void* __restrict__ w2,
    const void* __restrict__ w3,
    const void* __restrict__ cpw, const void* __restrict__ cw1,
    const void* __restrict__ cw2,
    const void* __restrict__ b1g, const void* __restrict__ b1b,
    const void* __restrict__ b1m, const void* __restrict__ b1v,
    const void* __restrict__ b2g, const void* __restrict__ b2b,
    const void* __restrict__ b2m, const void* __restrict__ b2v,
    unsigned short* __restrict__ y12,
    unsigned short* __restrict__ y3a,
    float* __restrict__ prep)
{
    __shared__ uintx4 frag[8 * 4 * 64];    // [s][t][lane], 32 KB
    const int tid = threadIdx.x;

    // prep: 16 blocks x 196 px each; block 0 also copies CP|W1|W2.
    if (blockIdx.x < 16) {
        if (blockIdx.x == 0) {
            for (int i = tid; i < 420; i += 384) {
                float v;
                if      (i < 4)   v = ldp(cpw, i,        ISB);
                else if (i < 292) v = ldp(cw1, i - 4,    ISB);
                else              v = ldp(cw2, i - 292,  ISB);
                prep[i] = v;
            }
        }
        const int i0 = blockIdx.x * 196;
        if (tid < 196) {
            const int i = i0 + tid;
            float a1 = ldp(b1g, i, ISB) * rsqrtf(ldp(b1v, i, ISB) + 1e-3f);
            float c1 = ldp(b1b, i, ISB) - ldp(b1m, i, ISB) * a1;
            float a2 = ldp(b2g, i, ISB) * rsqrtf(ldp(b2v, i, ISB) + 1e-3f);
            float c2 = ldp(b2b, i, ISB) - ldp(b2m, i, ISB) * a2;
            prep[P_BN + i]          = a1;
            prep[P_BN + HW + i]     = c1;
            prep[P_BN + 2 * HW + i] = a2;
            prep[P_BN + 3 * HW + i] = c2;
        }
    }

    // block = one (n, px0); the 6 waves are the 6 row-tiles.
    const int n    = blockIdx.x / 49;
    const int pt   = blockIdx.x - n * 49;
    const int px0  = pt * 64;                      // 49 * 64 = 3136 exact
    const int rt   = tid >> 6;                     // 0..5, wave-uniform
    const int lane = tid & 63;
    const int col  = lane & 15, quad = lane >> 4;

    const size_t xpx = (size_t)n * 256 * HW + px0 + 4 * col;

    // ---- staging: wave rt builds stage rt (waves 0,1 also stages 6,7) ----
    stage_one<ISB>(x, xpx, rt, quad, lane, frag);
    if (rt < 2) stage_one<ISB>(x, xpx, 6 + rt, quad, lane, frag);

    const void* wp; int ro;
    if      (rt == 0) { wp = w1; ro = 0;  }
    else if (rt == 1) { wp = w2; ro = 0;  }
    else if (rt == 2) { wp = w3; ro = 0;  }
    else if (rt == 3) { wp = w3; ro = 16; }
    else if (rt == 4) { wp = w3; ro = 32; }
    else              { wp = w3; ro = 48; }
    const int arow = ro + col;

    // first A-fragment issued before the barrier (latency under the sync)
    bf16x8 a0 = load_a<ISB>(wp, arow, quad, 0);

    __syncthreads();

    // ---- compute: LDS + MFMA, A streamed with 1-deep prefetch ----
    floatx4 acc[4] = {};
    #pragma unroll
    for (int s = 0; s < 8; ++s) {
        bf16x8 a1v = (s < 7) ? load_a<ISB>(wp, arow, quad, s + 1) : a0;
        uintx4 f[4];
        #pragma unroll
        for (int t = 0; t < 4; ++t)
            f[t] = frag[(s * 4 + t) * 64 + lane];
        #pragma unroll
        for (int t = 0; t < 4; ++t)
            acc[t] = __builtin_amdgcn_mfma_f32_16x16x32_bf16(
                a0, __builtin_bit_cast(bf16x8, f[t]), acc[t], 0, 0, 0);
        a0 = a1v;
    }

    // D: ch = 16*rt + quad*4 + g, px = px0 + 4*col + tt
    const int chq = quad * 4;
    #pragma unroll
    for (int tt = 0; tt < 4; ++tt) {
        const int px = px0 + 4 * col + tt;
        ushort4v pk;
        #pragma unroll
        for (int g = 0; g < 4; ++g) pk[g] = f2bf(acc[tt][g]);
        if (rt < 2) {
            *(ushort4v*)(y12 + ((size_t)n * HW + px) * 32 + rt * 16 + chq) = pk;
        } else {
            const int k8 = 2 * (rt - 2) + (quad >> 1);
            *(ushort4v*)(y3a + (((size_t)n * 8 + k8) * HW + px) * 8 + (quad & 1) * 4) = pk;
        }
    }
}

// ---------------------------------------------------------------------------
// Fused attention v3 — VERBATIM revert to the round-7 version (proven
// ~26 us as part of the 142.1 total). Round-9's v5 used a SATISFIABLE
// (512,8) min-waves contract -> compiler crushed VGPR to 32 (live set
// ~50-60) -> scratch spill: WRITE 12.5->29.8MB, dur 90us + a 193us
// first-dispatch scratch-alloc. Note (576,8)'s min is UNSATISFIABLE for
// 9-wave blocks, so the compiler allocates naturally here — that is why
// this version works. Do not "fix" the 8.
// ---------------------------------------------------------------------------
template <int ISB>
__global__ __launch_bounds__(576, 8) void attn_kernel(
    const unsigned short* __restrict__ y12,
    const unsigned short* __restrict__ y3a,
    const float* __restrict__ prep,
    void* __restrict__ out)
{
    __shared__ float wsm[64 * WS];
    const int tid = threadIdx.x;
    const int blk = blockIdx.x;
    const int n   = blk / 49;
    const int l0  = (blk - n * 49) * 64;

    // ---- phase 1: pre-softmax h2[8] per (pixel, j) ----
    {
        const int j = tid >> 6;            // 0..8, wave-uniform
        const int p = tid & 63;
        const int l = l0 + p;
        const int h = l / 56, w = l - h * 56;
        const int dy = j / 3 - 1, dx = j - (j / 3) * 3 - 1;
        int hh = h + dy; hh = (hh < 0) ? -hh : ((hh > 55) ? 110 - hh : hh);
        int ww = w + dx; ww = (ww < 0) ? -ww : ((ww > 55) ? 110 - ww : ww);
        const int nbr = hh * 56 + ww;

        const float a1 = prep[P_BN + l];
        const float c1 = prep[P_BN + HW + l];
        const float a2 = prep[P_BN + 2 * HW + l];
        const float c2 = prep[P_BN + 3 * HW + l];

        const unsigned short* y1p = y12 + ((size_t)n * HW + l) * 32;
        const unsigned short* y2p = y12 + ((size_t)n * HW + nbr) * 32 + 16;

        // fused unpack->rel per 8-wide half: only 2 uint4 + rel live (VGPR).
        float rel[18];
        #pragma unroll
        for (int half = 0; half < 2; ++half) {
            uint4 u1 = *(const uint4*)(y1p + 8 * half);
            uint4 u2 = *(const uint4*)(y2p + 8 * half);
            float t1[8], t2[8];
            unp8(u1, t1);
            unp8(u2, t2);
            #pragma unroll
            for (int c = 0; c < 8; ++c)
                rel[8 * half + c] = fmaxf(fmaf(t1[c] - t2[c], a1, c1), 0.f);
        }
        const float dlw = (float)(w - ww) * (2.0f / 55.0f);
        const float dlh = (float)(h - hh) * (2.0f / 55.0f);
        rel[16] = fmaxf(fmaf(prep[P_CP + 0] * dlw + prep[P_CP + 1] * dlh, a1, c1), 0.f);
        rel[17] = fmaxf(fmaf(prep[P_CP + 2] * dlw + prep[P_CP + 3] * dlh, a1, c1), 0.f);

        float h1[16];
        #pragma unroll
        for (int o = 0; o < 16; ++o) {
            float s = 0.f;
            #pragma unroll
            for (int c = 0; c < 18; ++c)
                s = fmaf(prep[P_W1 + o * 18 + c], rel[c], s);
            h1[o] = fmaxf(fmaf(s, a2, c2), 0.f);
        }
        float h2[8];
        #pragma unroll
        for (int o2 = 0; o2 < 8; ++o2) {
            float s = 0.f;
            #pragma unroll
            for (int o = 0; o < 16; ++o)
                s = fmaf(prep[P_W2 + o2 * 16 + o], h1[o], s);
            h2[o2] = s;
        }
        float* wpt = &wsm[p * WS + j * 8];
        *(floatx4*)wpt       = *(floatx4*)&h2[0];
        *(floatx4*)(wpt + 4) = *(floatx4*)&h2[4];
    }
    __syncthreads();

    // ---- phase 2: softmax over j ----
    if (tid < 512) {
        const int c = tid & 7, p = tid >> 3;
        float v[9];
        #pragma unroll
        for (int j = 0; j < 9; ++j) v[j] = wsm[p * WS + j * 8 + c];
        float m = v[0];
        #pragma unroll
        for (int j = 1; j < 9; ++j) m = fmaxf(m, v[j]);
        float s = 0.f;
        #pragma unroll
        for (int j = 0; j < 9; ++j) { v[j] = __expf(v[j] - m); s += v[j]; }
        const float inv = 1.f / s;
        #pragma unroll
        for (int j = 0; j < 9; ++j) wsm[p * WS + j * 8 + c] = v[j] * inv;
    }
    __syncthreads();

    // ---- phase 3: aggregation, y3a reads 16 B/lane contiguous per wave ----
    if (tid < 512) {
        const int p  = tid & 63;
        const int k8 = tid >> 6;           // wave-uniform channel-group of 8
        const int l = l0 + p;
        const int h = l / 56, w = l - h * 56;
        int nbr[9];
        #pragma unroll
        for (int dy = 0; dy < 3; ++dy)
            #pragma unroll
            for (int dx = 0; dx < 3; ++dx) {
                int hh = h + dy - 1; hh = (hh < 0) ? -hh : ((hh > 55) ? 110 - hh : hh);
                int ww = w + dx - 1; ww = (ww < 0) ? -ww : ((ww > 55) ? 110 - ww : ww);
                nbr[dy * 3 + dx] = hh * 56 + ww;
            }
        const unsigned short* y3b = y3a + ((size_t)n * 8 + k8) * HW * 8;
        float acc8[8];
        #pragma unroll
        for (int k = 0; k < 8; ++k) acc8[k] = 0.f;
        #pragma unroll
        for (int j = 0; j < 9; ++j) {
            uint4 u = *(const uint4*)(y3b + (size_t)nbr[j] * 8);
            float yv[8];
            unp8(u, yv);
            const float* wpt = &wsm[p * WS + j * 8];
            #pragma unroll
            for (int k = 0; k < 8; ++k)
                acc8[k] = fmaf(wpt[k], yv[k], acc8[k]);
        }
        const size_t obase = ((size_t)n * 64 + k8 * 8) * HW + l;
        #pragma unroll
        for (int k = 0; k < 8; ++k) {
            if (ISB) ((unsigned short*)out)[obase + (size_t)k * HW] = f2bf(acc8[k]);
            else     ((float*)out)[obase + (size_t)k * HW]          = acc8[k];
        }
    }
}

extern "C" void kernel_launch(void* const* d_in, const int* in_sizes, int n_in,
                              void* d_out, int out_size, void* d_ws, size_t ws_size,
                              hipStream_t stream)
{
    const size_t y12B = (size_t)16 * HW * 32 * 2;      // 3,211,264 B
    const size_t y3aB = (size_t)16 * 8 * HW * 8 * 2;   // 6,422,528 B

    unsigned short* y12 = (unsigned short*)d_ws;
    unsigned short* y3a = (unsigned short*)((char*)d_ws + y12B);
    float* prep = (float*)((char*)d_ws + y12B + y3aB);

    // dtype detect on HOST: bn1_var is [3136] -> 6272 B bf16, 12544 B fp32.
    const int isb = (in_sizes[10] == HW * 2);

    if (isb) {
        proj_kernel<1><<<dim3(784), dim3(384), 0, stream>>>(
            d_in[0], d_in[1], d_in[2], d_in[3],
            d_in[4], d_in[5], d_in[6],
            d_in[7], d_in[8], d_in[9], d_in[10],
            d_in[11], d_in[12], d_in[13], d_in[14],
            y12, y3a, prep);
        attn_kernel<1><<<dim3(784), dim3(576), 0, stream>>>(y12, y3a, prep, d_out);
    } else {
        proj_kernel<0><<<dim3(784), dim3(384), 0, stream>>>(
            d_in[0], d_in[1], d_in[2], d_in[3],
            d_in[4], d_in[5], d_in[6],
            d_in[7], d_in[8], d_in[9], d_in[10],
            d_in[11], d_in[12], d_in[13], d_in[14],
            y12, y3a, prep);
        attn_kernel<0><<<dim3(784), dim3(576), 0, stream>>>(y12, y3a, prep, d_out);
    }
}